// Round 9
// baseline (325.455 us; speedup 1.0000x reference)
//
#include <hip/hip_runtime.h>

// GRU last-hidden: B=1024, C=64, T=1024, H=32, G=96, fp32.
// x:(B,64,1024) W_ih:(96,64) W_hh:(96,32) b_ih,b_hh:(96) out:(B,32)
//
// 256 blocks x 512 threads; block = 4 batches, 8 waves:
//   waves 0-3 = producers: gx tile (32t x 96g) via MFMA bf16 hi/lo 3-product.
//     R9: register-pressure squeeze — R8 spilled (WRITE_SIZE 20.6MB, scratch
//     reloads on the recurrence chain = 756cy/step measured vs ~250 modeled):
//       * mt-at-a-time (one m-tile's A-frags live: 16 VGPR not 32)
//       * B-frags loaded in pairs (8 live not 16)
//       * bias moved to LDS (biasc[96])
//       * sched_barrier(0) between m-tiles to stop the scheduler re-hoisting
//   waves 4-7 = consumers: EXACT R8 gate-split readlane recurrence (verified):
//     half0 r-matvec, half1 z-matvec, n redundant on both; h broadcast via 32
//     compile-time v_readlane (lanes 0-31 hold h); z shipped via 1 shfl_xor.
//     Only change: g-matvec uses 4 accumulators (8-deep FMA chain, was 16).
//
// LDS (157056 B):
//   wfH/wfL: W_ih MFMA B-frags bf16 hi/lo [2kt][6nt][64lane][8]  24576 B
//   xs:      x tiles [4 wave][64 c][32 t], t XOR-swizzled by (c>>3)&3  32768 B
//   gxs:     [2 buf][4 batch][32 t][97] packed [h*3+gate]          99328 B
//   biasc:   [96] b_ih + b_hh(r/z folded)                            384 B

typedef short bf16x8 __attribute__((ext_vector_type(8)));
typedef float f32x4  __attribute__((ext_vector_type(4)));

#define TT 32
#define GXS 97
#define LDS_BYTES 157056

#define GLL16(gp, lp)                                                        \
  __builtin_amdgcn_global_load_lds(                                          \
      (const __attribute__((address_space(1))) void*)(gp),                   \
      (__attribute__((address_space(3))) void*)(lp), 16, 0, 0)

static __device__ __forceinline__ short f2bf(float f) {   // RNE float->bf16
    unsigned u = __float_as_uint(f);
    u += 0x7fffu + ((u >> 16) & 1u);
    return (short)(u >> 16);
}
static __device__ __forceinline__ float bf2f(short s) {
    return __uint_as_float(((unsigned)(unsigned short)s) << 16);
}

__global__ __launch_bounds__(512) void gru_fused9(
    const float* __restrict__ x,
    const float* __restrict__ W_ih,
    const float* __restrict__ W_hh,
    const float* __restrict__ b_ih,
    const float* __restrict__ b_hh,
    float* __restrict__ out)
{
    extern __shared__ char smem[];
    short* wfH   = (short*)smem;                    // 768 frags * 8 shorts
    short* wfL   = (short*)(smem + 12288);
    float* xs    = (float*)(smem + 24576);          // 4 * 2048 floats
    float* gxs   = (float*)(smem + 57344);          // 2*4*32*97 floats
    float* biasc = (float*)(smem + 156672);         // 96 floats

    const int tid  = threadIdx.x;
    const int wid  = tid >> 6;
    const int lane = tid & 63;
    const int bid  = blockIdx.x;

    // ---- one-time: W_ih -> bf16 hi/lo MFMA B-fragments in LDS ----
    for (int f = tid; f < 768; f += 512) {
        int slot = f & 63, ktnt = f >> 6;
        int kt = ktnt / 6, nt = ktnt - kt * 6;
        int g  = nt * 16 + (slot & 15);
        int c0 = kt * 32 + (slot >> 4) * 8;
        const float* wr = W_ih + g * 64 + c0;
        bf16x8 hi, lo;
        #pragma unroll
        for (int j = 0; j < 8; ++j) {
            float v  = wr[j];
            short hb = f2bf(v);
            hi[j] = hb;
            lo[j] = f2bf(v - bf2f(hb));
        }
        *(bf16x8*)(wfH + f * 8) = hi;
        *(bf16x8*)(wfL + f * 8) = lo;
    }
    if (tid < 96) biasc[tid] = b_ih[tid] + (tid < 64 ? b_hh[tid] : 0.f);

    // ================= producer state =================
    const float* xb = nullptr;
    if (wid < 4) xb = x + (size_t)(bid * 4 + wid) * 64 * 1024;

    // ================= consumer state (gate-split, R8-verified) ==========
    const int h  = lane & 31;
    const int h3 = h * 3;
    float wg_[32], wn_[32];     // wg_: r-row (half0) or z-row (half1); wn_: n-row
    float bhn = 0.f, hout = 0.f;
    if (wid >= 4) {
        const int grow = (lane < 32) ? h : (32 + h);
        #pragma unroll
        for (int j = 0; j < 32; ++j) {
            wg_[j] = W_hh[grow * 32 + j];
            wn_[j] = W_hh[(64 + h) * 32 + j];
        }
        bhn = b_hh[64 + h];
    }

    // async x-tile: lands as xs[c][t ^ (((c>>3)&3)<<2)] (XOR applied to the
    // GLOBAL source t-offset; LDS dest stays linear) -> conflict-free A-reads
    auto load_xtile = [&](int tile) {
        const int tbase = tile * TT;
        const int c_lo  = lane >> 3;
        #pragma unroll
        for (int i = 0; i < 8; ++i) {
            const int toff = ((lane & 7) ^ (i & 3)) << 2;
            const float* gp = xb + (i * 8 + c_lo) * 1024 + tbase + toff;
            float* lp = xs + wid * 2048 + i * 256;   // wave-uniform base
            GLL16(gp, lp);
        }
    };

    // producer: gx tile via MFMA, mt-at-a-time, paired B-frags, bias from LDS
    auto stage1 = [&](int buf, int prefetch_tile) {
        float* gb = gxs + buf * 12416 + wid * 3104;
        #pragma unroll
        for (int mt = 0; mt < 2; ++mt) {
            bf16x8 ah[2], al[2];
            const int tS = (mt * 16 + (lane & 15)) ^ ((lane >> 4) << 2);
            #pragma unroll
            for (int kt = 0; kt < 2; ++kt) {
                const int cb = kt * 32 + (lane >> 4) * 8;
                float xf[8];
                #pragma unroll
                for (int j = 0; j < 8; ++j)
                    xf[j] = xs[wid * 2048 + (cb + j) * 32 + tS];
                #pragma unroll
                for (int j = 0; j < 8; ++j) {
                    short hb_ = f2bf(xf[j]);
                    ah[kt][j] = hb_;
                    al[kt][j] = f2bf(xf[j] - bf2f(hb_));
                }
            }
            const int row0 = mt * 16 + ((lane >> 4) << 2);
            #pragma unroll
            for (int nt = 0; nt < 6; ++nt) {
                const int g   = nt * 16 + (lane & 15);
                const int off = (g & 31) * 3 + (g >> 5);   // packed column
                const float bias = biasc[g];
                f32x4 acc = {bias, bias, bias, bias};
                bf16x8 b0 = *(const bf16x8*)(wfH + ((nt)     * 64 + lane) * 8);
                bf16x8 b1 = *(const bf16x8*)(wfH + ((6 + nt) * 64 + lane) * 8);
                acc = __builtin_amdgcn_mfma_f32_16x16x32_bf16(ah[0], b0, acc, 0, 0, 0);
                acc = __builtin_amdgcn_mfma_f32_16x16x32_bf16(ah[1], b1, acc, 0, 0, 0);
                acc = __builtin_amdgcn_mfma_f32_16x16x32_bf16(al[0], b0, acc, 0, 0, 0);
                acc = __builtin_amdgcn_mfma_f32_16x16x32_bf16(al[1], b1, acc, 0, 0, 0);
                b0 = *(const bf16x8*)(wfL + ((nt)     * 64 + lane) * 8);
                b1 = *(const bf16x8*)(wfL + ((6 + nt) * 64 + lane) * 8);
                acc = __builtin_amdgcn_mfma_f32_16x16x32_bf16(ah[0], b0, acc, 0, 0, 0);
                acc = __builtin_amdgcn_mfma_f32_16x16x32_bf16(ah[1], b1, acc, 0, 0, 0);
                // C layout: col = lane&15 (g), row = (lane>>4)*4 + reg (t)
                #pragma unroll
                for (int j = 0; j < 4; ++j)
                    gb[(row0 + j) * GXS + off] = acc[j];
            }
            if (mt == 0) __builtin_amdgcn_sched_barrier(0);  // cap reg pressure
        }
        // all xs reads drained -> safe to overwrite own xs region
        asm volatile("s_waitcnt lgkmcnt(0)" ::: "memory");
        if (prefetch_tile >= 0) load_xtile(prefetch_tile);
    };

    // consumer: 32 steps; h broadcast via 32 compile-time readlanes (SGPR),
    // z matvec shipped half1->half0 via one shfl_xor. No LDS in the chain.
    auto stage2 = [&](int buf) {
        const float* gb = gxs + buf * 12416 + (wid - 4) * 3104;
        #pragma unroll 2
        for (int s = 0; s < TT; ++s) {
            const float* row = gb + s * GXS + h3;
            float xr = row[0], xz = row[1], xn = row[2];
            float a0 = 0.f, a1 = 0.f, a2 = 0.f, a3 = 0.f, n0 = 0.f, n1 = 0.f;
            const int hb = __float_as_int(hout);
            #pragma unroll
            for (int j = 0; j < 32; j += 4) {
                float s0 = __int_as_float(__builtin_amdgcn_readlane(hb, j));
                float s1 = __int_as_float(__builtin_amdgcn_readlane(hb, j + 1));
                float s2 = __int_as_float(__builtin_amdgcn_readlane(hb, j + 2));
                float s3 = __int_as_float(__builtin_amdgcn_readlane(hb, j + 3));
                a0 = fmaf(wg_[j],     s0, a0);
                a1 = fmaf(wg_[j + 1], s1, a1);
                a2 = fmaf(wg_[j + 2], s2, a2);
                a3 = fmaf(wg_[j + 3], s3, a3);
                n0 = fmaf(wn_[j],     s0, n0);
                n1 = fmaf(wn_[j + 1], s1, n1);
                n0 = fmaf(wn_[j + 2], s2, n0);
                n1 = fmaf(wn_[j + 3], s3, n1);
            }
            float accA = (a0 + a1) + (a2 + a3);      // r (half0) / z (half1)
            float accN = n0 + n1;                    // n (both halves)
            float accZ = __shfl_xor(accA, 32, 64);   // half0 receives z matvec
            if (lane < 32) {
                float r  = __builtin_amdgcn_rcpf(1.f + __expf(-(xr + accA)));
                float z  = __builtin_amdgcn_rcpf(1.f + __expf(-(xz + accZ)));
                float nx = fmaf(r, accN + bhn, xn);
                float n  = 1.f - 2.f * __builtin_amdgcn_rcpf(__expf(2.f * nx) + 1.f);
                hout = n + z * (hout - n);           // lanes 0-31 hold h[0..31]
            }
        }
    };

    // ================= pipeline =================
    if (wid < 4) load_xtile(0);
    __syncthreads();                    // wfrag+bias ready; xs = tile 0

    if (wid < 4) stage1(0, 1);          // gxs[0] = tile 0; prefetch tile 1
    __syncthreads();                    // gxs[0] visible; xs = tile 1

    for (int k = 0; k < 32; ++k) {
        if (wid >= 4) {
            stage2(k & 1);
        } else if (k < 31) {
            stage1((k + 1) & 1, (k < 30) ? (k + 2) : -1);
        }
        __syncthreads();
    }

    if (wid >= 4 && lane < 32)
        out[(bid * 4 + (wid - 4)) * 32 + lane] = hout;
}

extern "C" void kernel_launch(void* const* d_in, const int* in_sizes, int n_in,
                              void* d_out, int out_size, void* d_ws, size_t ws_size,
                              hipStream_t stream) {
    const float* x    = (const float*)d_in[0];
    const float* W_ih = (const float*)d_in[1];
    const float* W_hh = (const float*)d_in[2];
    const float* b_ih = (const float*)d_in[3];
    const float* b_hh = (const float*)d_in[4];
    float* out = (float*)d_out;

    hipFuncSetAttribute((const void*)gru_fused9,
                        hipFuncAttributeMaxDynamicSharedMemorySize, LDS_BYTES);
    gru_fused9<<<256, 512, LDS_BYTES, stream>>>(x, W_ih, W_hh, b_ih, b_hh, out);
}

// Round 10
// 264.087 us; speedup vs baseline: 1.2324x; 1.2324x over previous
//
#include <hip/hip_runtime.h>

// GRU last-hidden: B=1024, C=64, T=1024, H=32, G=96, fp32.
// x:(B,64,1024) W_ih:(96,64) W_hh:(96,32) b_ih,b_hh:(96) out:(B,32)
//
// 256 blocks x 512 threads; block = 4 batches, 8 waves:
//   waves 0-3 = producers: gx tile (32t x 96g) via MFMA bf16 hi/lo 3-product
//     (R9 register-squeezed version: mt-at-a-time, paired B-frags, bias in
//      LDS, sched_barrier between m-tiles -> no spill, WRITE_SIZE clean).
//   waves 4-7 = consumers: R8/R9-verified gate-split readlane recurrence.
//     R10 chain cleanup (R9 showed spill was off-path; 762cy/step is chain):
//       * gx values for step s+1 prefetched at iteration start -> the 3
//         ds_reads (and their queuing behind producer b128 bursts on the
//         CU-shared LDS pipe) leave the serial h-chain
//       * s_setprio(1) around stage2: consumers win SIMD issue arbitration
//         over co-resident producers (T5 regime: role-split waves)
//       * n-matvec 4 accumulators (8-deep FMA chain, was 16)
//
// LDS (157056 B):
//   wfH/wfL: W_ih MFMA B-frags bf16 hi/lo [2kt][6nt][64lane][8]  24576 B
//   xs:      x tiles [4 wave][64 c][32 t], t XOR-swizzled by (c>>3)&3  32768 B
//   gxs:     [2 buf][4 batch][32 t][97] packed [h*3+gate]          99328 B
//   biasc:   [96] b_ih + b_hh(r/z folded)                            384 B

typedef short bf16x8 __attribute__((ext_vector_type(8)));
typedef float f32x4  __attribute__((ext_vector_type(4)));

#define TT 32
#define GXS 97
#define LDS_BYTES 157056

#define GLL16(gp, lp)                                                        \
  __builtin_amdgcn_global_load_lds(                                          \
      (const __attribute__((address_space(1))) void*)(gp),                   \
      (__attribute__((address_space(3))) void*)(lp), 16, 0, 0)

static __device__ __forceinline__ short f2bf(float f) {   // RNE float->bf16
    unsigned u = __float_as_uint(f);
    u += 0x7fffu + ((u >> 16) & 1u);
    return (short)(u >> 16);
}
static __device__ __forceinline__ float bf2f(short s) {
    return __uint_as_float(((unsigned)(unsigned short)s) << 16);
}

__global__ __launch_bounds__(512) void gru_fused10(
    const float* __restrict__ x,
    const float* __restrict__ W_ih,
    const float* __restrict__ W_hh,
    const float* __restrict__ b_ih,
    const float* __restrict__ b_hh,
    float* __restrict__ out)
{
    extern __shared__ char smem[];
    short* wfH   = (short*)smem;                    // 768 frags * 8 shorts
    short* wfL   = (short*)(smem + 12288);
    float* xs    = (float*)(smem + 24576);          // 4 * 2048 floats
    float* gxs   = (float*)(smem + 57344);          // 2*4*32*97 floats
    float* biasc = (float*)(smem + 156672);         // 96 floats

    const int tid  = threadIdx.x;
    const int wid  = tid >> 6;
    const int lane = tid & 63;
    const int bid  = blockIdx.x;

    // ---- one-time: W_ih -> bf16 hi/lo MFMA B-fragments in LDS ----
    for (int f = tid; f < 768; f += 512) {
        int slot = f & 63, ktnt = f >> 6;
        int kt = ktnt / 6, nt = ktnt - kt * 6;
        int g  = nt * 16 + (slot & 15);
        int c0 = kt * 32 + (slot >> 4) * 8;
        const float* wr = W_ih + g * 64 + c0;
        bf16x8 hi, lo;
        #pragma unroll
        for (int j = 0; j < 8; ++j) {
            float v  = wr[j];
            short hb = f2bf(v);
            hi[j] = hb;
            lo[j] = f2bf(v - bf2f(hb));
        }
        *(bf16x8*)(wfH + f * 8) = hi;
        *(bf16x8*)(wfL + f * 8) = lo;
    }
    if (tid < 96) biasc[tid] = b_ih[tid] + (tid < 64 ? b_hh[tid] : 0.f);

    // ================= producer state =================
    const float* xb = nullptr;
    if (wid < 4) xb = x + (size_t)(bid * 4 + wid) * 64 * 1024;

    // ================= consumer state (gate-split, R8-verified) ==========
    const int h  = lane & 31;
    const int h3 = h * 3;
    float wg_[32], wn_[32];     // wg_: r-row (half0) or z-row (half1); wn_: n-row
    float bhn = 0.f, hout = 0.f;
    if (wid >= 4) {
        const int grow = (lane < 32) ? h : (32 + h);
        #pragma unroll
        for (int j = 0; j < 32; ++j) {
            wg_[j] = W_hh[grow * 32 + j];
            wn_[j] = W_hh[(64 + h) * 32 + j];
        }
        bhn = b_hh[64 + h];
    }

    // async x-tile: lands as xs[c][t ^ (((c>>3)&3)<<2)] (XOR applied to the
    // GLOBAL source t-offset; LDS dest stays linear) -> conflict-free A-reads
    auto load_xtile = [&](int tile) {
        const int tbase = tile * TT;
        const int c_lo  = lane >> 3;
        #pragma unroll
        for (int i = 0; i < 8; ++i) {
            const int toff = ((lane & 7) ^ (i & 3)) << 2;
            const float* gp = xb + (i * 8 + c_lo) * 1024 + tbase + toff;
            float* lp = xs + wid * 2048 + i * 256;   // wave-uniform base
            GLL16(gp, lp);
        }
    };

    // producer: gx tile via MFMA, mt-at-a-time, paired B-frags, bias from LDS
    auto stage1 = [&](int buf, int prefetch_tile) {
        float* gb = gxs + buf * 12416 + wid * 3104;
        #pragma unroll
        for (int mt = 0; mt < 2; ++mt) {
            bf16x8 ah[2], al[2];
            const int tS = (mt * 16 + (lane & 15)) ^ ((lane >> 4) << 2);
            #pragma unroll
            for (int kt = 0; kt < 2; ++kt) {
                const int cb = kt * 32 + (lane >> 4) * 8;
                float xf[8];
                #pragma unroll
                for (int j = 0; j < 8; ++j)
                    xf[j] = xs[wid * 2048 + (cb + j) * 32 + tS];
                #pragma unroll
                for (int j = 0; j < 8; ++j) {
                    short hb_ = f2bf(xf[j]);
                    ah[kt][j] = hb_;
                    al[kt][j] = f2bf(xf[j] - bf2f(hb_));
                }
            }
            const int row0 = mt * 16 + ((lane >> 4) << 2);
            #pragma unroll
            for (int nt = 0; nt < 6; ++nt) {
                const int g   = nt * 16 + (lane & 15);
                const int off = (g & 31) * 3 + (g >> 5);   // packed column
                const float bias = biasc[g];
                f32x4 acc = {bias, bias, bias, bias};
                bf16x8 b0 = *(const bf16x8*)(wfH + ((nt)     * 64 + lane) * 8);
                bf16x8 b1 = *(const bf16x8*)(wfH + ((6 + nt) * 64 + lane) * 8);
                acc = __builtin_amdgcn_mfma_f32_16x16x32_bf16(ah[0], b0, acc, 0, 0, 0);
                acc = __builtin_amdgcn_mfma_f32_16x16x32_bf16(ah[1], b1, acc, 0, 0, 0);
                acc = __builtin_amdgcn_mfma_f32_16x16x32_bf16(al[0], b0, acc, 0, 0, 0);
                acc = __builtin_amdgcn_mfma_f32_16x16x32_bf16(al[1], b1, acc, 0, 0, 0);
                b0 = *(const bf16x8*)(wfL + ((nt)     * 64 + lane) * 8);
                b1 = *(const bf16x8*)(wfL + ((6 + nt) * 64 + lane) * 8);
                acc = __builtin_amdgcn_mfma_f32_16x16x32_bf16(ah[0], b0, acc, 0, 0, 0);
                acc = __builtin_amdgcn_mfma_f32_16x16x32_bf16(ah[1], b1, acc, 0, 0, 0);
                // C layout: col = lane&15 (g), row = (lane>>4)*4 + reg (t)
                #pragma unroll
                for (int j = 0; j < 4; ++j)
                    gb[(row0 + j) * GXS + off] = acc[j];
            }
            if (mt == 0) __builtin_amdgcn_sched_barrier(0);  // cap reg pressure
        }
        // all xs reads drained -> safe to overwrite own xs region
        asm volatile("s_waitcnt lgkmcnt(0)" ::: "memory");
        if (prefetch_tile >= 0) load_xtile(prefetch_tile);
    };

    // consumer: 32 steps; h broadcast via 32 compile-time readlanes (SGPR),
    // z shipped half1->half0 via one shfl_xor. gx values prefetched one step
    // ahead so no DS latency sits on the serial h-chain.
    auto stage2 = [&](int buf) {
        const float* gb = gxs + buf * 12416 + (wid - 4) * 3104;
        __builtin_amdgcn_s_setprio(1);           // consumers own the SIMD
        float xr = gb[h3], xz = gb[h3 + 1], xn = gb[h3 + 2];   // s = 0
        #pragma unroll 4
        for (int s = 0; s < TT; ++s) {
            // prefetch step s+1 (independent of the h-chain)
            float xr_n = 0.f, xz_n = 0.f, xn_n = 0.f;
            if (s < TT - 1) {
                const float* nrow = gb + (s + 1) * GXS + h3;
                xr_n = nrow[0]; xz_n = nrow[1]; xn_n = nrow[2];
            }
            float a0 = 0.f, a1 = 0.f, a2 = 0.f, a3 = 0.f;
            float n0 = 0.f, n1 = 0.f, n2 = 0.f, n3 = 0.f;
            const int hb = __float_as_int(hout);
            #pragma unroll
            for (int j = 0; j < 32; j += 4) {
                float s0 = __int_as_float(__builtin_amdgcn_readlane(hb, j));
                float s1 = __int_as_float(__builtin_amdgcn_readlane(hb, j + 1));
                float s2 = __int_as_float(__builtin_amdgcn_readlane(hb, j + 2));
                float s3 = __int_as_float(__builtin_amdgcn_readlane(hb, j + 3));
                a0 = fmaf(wg_[j],     s0, a0);
                a1 = fmaf(wg_[j + 1], s1, a1);
                a2 = fmaf(wg_[j + 2], s2, a2);
                a3 = fmaf(wg_[j + 3], s3, a3);
                n0 = fmaf(wn_[j],     s0, n0);
                n1 = fmaf(wn_[j + 1], s1, n1);
                n2 = fmaf(wn_[j + 2], s2, n2);
                n3 = fmaf(wn_[j + 3], s3, n3);
            }
            float accA = (a0 + a1) + (a2 + a3);      // r (half0) / z (half1)
            float accN = (n0 + n1) + (n2 + n3);      // n (both halves)
            float accZ = __shfl_xor(accA, 32, 64);   // half0 receives z matvec
            if (lane < 32) {
                float r  = __builtin_amdgcn_rcpf(1.f + __expf(-(xr + accA)));
                float z  = __builtin_amdgcn_rcpf(1.f + __expf(-(xz + accZ)));
                float nx = fmaf(r, accN + bhn, xn);
                float n  = 1.f - 2.f * __builtin_amdgcn_rcpf(__expf(2.f * nx) + 1.f);
                hout = n + z * (hout - n);           // lanes 0-31 hold h[0..31]
            }
            xr = xr_n; xz = xz_n; xn = xn_n;
        }
        __builtin_amdgcn_s_setprio(0);
    };

    // ================= pipeline =================
    if (wid < 4) load_xtile(0);
    __syncthreads();                    // wfrag+bias ready; xs = tile 0

    if (wid < 4) stage1(0, 1);          // gxs[0] = tile 0; prefetch tile 1
    __syncthreads();                    // gxs[0] visible; xs = tile 1

    for (int k = 0; k < 32; ++k) {
        if (wid >= 4) {
            stage2(k & 1);
        } else if (k < 31) {
            stage1((k + 1) & 1, (k < 30) ? (k + 2) : -1);
        }
        __syncthreads();
    }

    if (wid >= 4 && lane < 32)
        out[(bid * 4 + (wid - 4)) * 32 + lane] = hout;
}

extern "C" void kernel_launch(void* const* d_in, const int* in_sizes, int n_in,
                              void* d_out, int out_size, void* d_ws, size_t ws_size,
                              hipStream_t stream) {
    const float* x    = (const float*)d_in[0];
    const float* W_ih = (const float*)d_in[1];
    const float* W_hh = (const float*)d_in[2];
    const float* b_ih = (const float*)d_in[3];
    const float* b_hh = (const float*)d_in[4];
    float* out = (float*)d_out;

    hipFuncSetAttribute((const void*)gru_fused10,
                        hipFuncAttributeMaxDynamicSharedMemorySize, LDS_BYTES);
    gru_fused10<<<256, 512, LDS_BYTES, stream>>>(x, W_ih, W_hh, b_ih, b_hh, out);
}

// Round 11
// 252.856 us; speedup vs baseline: 1.2871x; 1.0444x over previous
//
#include <hip/hip_runtime.h>

// GRU last-hidden: B=1024, C=64, T=1024, H=32, G=96, fp32.
// x:(B,64,1024) W_ih:(96,64) W_hh:(96,32) b_ih,b_hh:(96) out:(B,32)
//
// 256 blocks x 512 threads; block = 4 batches, 8 waves:
//   waves 0-3 = producers: gx tile (32t x 96g) via MFMA bf16 hi/lo 3-product
//     (R9 register-squeezed). R11: xs swizzle at 8-col granularity
//     (^(group<<3), was ^(group<<2)) -> A-frag reads drop 4-way -> 2-way
//     bank conflict (2-way is free, m136).
//   waves 4-7 = consumers: R8-verified gate-split readlane recurrence.
//     R11 issue-count cuts (R10 showed VALUBusy 78% = issue-bound):
//       * matvec as f32x2 packed FMA (v_pk_fma_f32): 64 FMA -> 32 pk
//       * joint sigmoid: all lanes compute sigma(x_sel+accA) (half0=r,
//         half1=z), then ONE shfl ships finished z -> saves 1 exp + 1 rcp
//       * gx prefetch one step ahead + s_setprio(1) retained from R10
//
// LDS (157056 B):
//   wfH/wfL: W_ih MFMA B-frags bf16 hi/lo [2kt][6nt][64lane][8]  24576 B
//   xs:      x tiles [4 wave][64 c][32 t], t XOR-swizzled by ((c>>3)&3)<<3  32768 B
//   gxs:     [2 buf][4 batch][32 t][97] packed [h*3+gate]          99328 B
//   biasc:   [96] b_ih + b_hh(r/z folded)                            384 B

typedef short bf16x8 __attribute__((ext_vector_type(8)));
typedef float f32x4  __attribute__((ext_vector_type(4)));
typedef float f32x2  __attribute__((ext_vector_type(2)));

#define TT 32
#define GXS 97
#define LDS_BYTES 157056

#define GLL16(gp, lp)                                                        \
  __builtin_amdgcn_global_load_lds(                                          \
      (const __attribute__((address_space(1))) void*)(gp),                   \
      (__attribute__((address_space(3))) void*)(lp), 16, 0, 0)

static __device__ __forceinline__ short f2bf(float f) {   // RNE float->bf16
    unsigned u = __float_as_uint(f);
    u += 0x7fffu + ((u >> 16) & 1u);
    return (short)(u >> 16);
}
static __device__ __forceinline__ float bf2f(short s) {
    return __uint_as_float(((unsigned)(unsigned short)s) << 16);
}

__global__ __launch_bounds__(512) void gru_fused11(
    const float* __restrict__ x,
    const float* __restrict__ W_ih,
    const float* __restrict__ W_hh,
    const float* __restrict__ b_ih,
    const float* __restrict__ b_hh,
    float* __restrict__ out)
{
    extern __shared__ char smem[];
    short* wfH   = (short*)smem;                    // 768 frags * 8 shorts
    short* wfL   = (short*)(smem + 12288);
    float* xs    = (float*)(smem + 24576);          // 4 * 2048 floats
    float* gxs   = (float*)(smem + 57344);          // 2*4*32*97 floats
    float* biasc = (float*)(smem + 156672);         // 96 floats

    const int tid  = threadIdx.x;
    const int wid  = tid >> 6;
    const int lane = tid & 63;
    const int bid  = blockIdx.x;

    // ---- one-time: W_ih -> bf16 hi/lo MFMA B-fragments in LDS ----
    for (int f = tid; f < 768; f += 512) {
        int slot = f & 63, ktnt = f >> 6;
        int kt = ktnt / 6, nt = ktnt - kt * 6;
        int g  = nt * 16 + (slot & 15);
        int c0 = kt * 32 + (slot >> 4) * 8;
        const float* wr = W_ih + g * 64 + c0;
        bf16x8 hi, lo;
        #pragma unroll
        for (int j = 0; j < 8; ++j) {
            float v  = wr[j];
            short hb = f2bf(v);
            hi[j] = hb;
            lo[j] = f2bf(v - bf2f(hb));
        }
        *(bf16x8*)(wfH + f * 8) = hi;
        *(bf16x8*)(wfL + f * 8) = lo;
    }
    if (tid < 96) biasc[tid] = b_ih[tid] + (tid < 64 ? b_hh[tid] : 0.f);

    // ================= producer state =================
    const float* xb = nullptr;
    if (wid < 4) xb = x + (size_t)(bid * 4 + wid) * 64 * 1024;

    // ================= consumer state (gate-split, R8-verified) ==========
    const int h  = lane & 31;
    const int h3 = h * 3;
    f32x2 wg2[16], wn2[16];     // wg2: r-row (half0) / z-row (half1); wn2: n-row
    float bhn = 0.f, hout = 0.f;
    if (wid >= 4) {
        const int grow = (lane < 32) ? h : (32 + h);
        #pragma unroll
        for (int j = 0; j < 16; ++j) {
            wg2[j] = *(const f32x2*)(W_hh + grow * 32 + 2 * j);
            wn2[j] = *(const f32x2*)(W_hh + (64 + h) * 32 + 2 * j);
        }
        bhn = b_hh[64 + h];
    }

    // async x-tile: LDS[c][q] holds x[c][q ^ (((c>>3)&3)<<3)] (XOR applied
    // to the GLOBAL source t-offset; LDS dest stays linear). 8-col XOR
    // granularity -> A-frag reads are max 2-way bank conflict (free).
    auto load_xtile = [&](int tile) {
        const int tbase = tile * TT;
        const int c_lo  = lane >> 3;
        #pragma unroll
        for (int i = 0; i < 8; ++i) {
            const int toff = (((lane & 7) << 2) ^ ((i & 3) << 3));
            const float* gp = xb + (i * 8 + c_lo) * 1024 + tbase + toff;
            float* lp = xs + wid * 2048 + i * 256;   // wave-uniform base
            GLL16(gp, lp);
        }
    };

    // producer: gx tile via MFMA, mt-at-a-time, paired B-frags, bias from LDS
    auto stage1 = [&](int buf, int prefetch_tile) {
        float* gb = gxs + buf * 12416 + wid * 3104;
        #pragma unroll
        for (int mt = 0; mt < 2; ++mt) {
            bf16x8 ah[2], al[2];
            // want x[c][mt*16+(lane&15)]; stored at q = t ^ (g<<3), g=lane>>4
            const int tS = (mt * 16 + (lane & 15)) ^ ((lane >> 4) << 3);
            #pragma unroll
            for (int kt = 0; kt < 2; ++kt) {
                const int cb = kt * 32 + (lane >> 4) * 8;
                float xf[8];
                #pragma unroll
                for (int j = 0; j < 8; ++j)
                    xf[j] = xs[wid * 2048 + (cb + j) * 32 + tS];
                #pragma unroll
                for (int j = 0; j < 8; ++j) {
                    short hb_ = f2bf(xf[j]);
                    ah[kt][j] = hb_;
                    al[kt][j] = f2bf(xf[j] - bf2f(hb_));
                }
            }
            const int row0 = mt * 16 + ((lane >> 4) << 2);
            #pragma unroll
            for (int nt = 0; nt < 6; ++nt) {
                const int g   = nt * 16 + (lane & 15);
                const int off = (g & 31) * 3 + (g >> 5);   // packed column
                const float bias = biasc[g];
                f32x4 acc = {bias, bias, bias, bias};
                bf16x8 b0 = *(const bf16x8*)(wfH + ((nt)     * 64 + lane) * 8);
                bf16x8 b1 = *(const bf16x8*)(wfH + ((6 + nt) * 64 + lane) * 8);
                acc = __builtin_amdgcn_mfma_f32_16x16x32_bf16(ah[0], b0, acc, 0, 0, 0);
                acc = __builtin_amdgcn_mfma_f32_16x16x32_bf16(ah[1], b1, acc, 0, 0, 0);
                acc = __builtin_amdgcn_mfma_f32_16x16x32_bf16(al[0], b0, acc, 0, 0, 0);
                acc = __builtin_amdgcn_mfma_f32_16x16x32_bf16(al[1], b1, acc, 0, 0, 0);
                b0 = *(const bf16x8*)(wfL + ((nt)     * 64 + lane) * 8);
                b1 = *(const bf16x8*)(wfL + ((6 + nt) * 64 + lane) * 8);
                acc = __builtin_amdgcn_mfma_f32_16x16x32_bf16(ah[0], b0, acc, 0, 0, 0);
                acc = __builtin_amdgcn_mfma_f32_16x16x32_bf16(ah[1], b1, acc, 0, 0, 0);
                // C layout: col = lane&15 (g), row = (lane>>4)*4 + reg (t)
                #pragma unroll
                for (int j = 0; j < 4; ++j)
                    gb[(row0 + j) * GXS + off] = acc[j];
            }
            if (mt == 0) __builtin_amdgcn_sched_barrier(0);  // cap reg pressure
        }
        // all xs reads drained -> safe to overwrite own xs region
        asm volatile("s_waitcnt lgkmcnt(0)" ::: "memory");
        if (prefetch_tile >= 0) load_xtile(prefetch_tile);
    };

    // consumer: 32 steps; 32 readlane + 32 pk_fma matvec; joint sigmoid on
    // both halves then one shfl ships z; gx prefetched one step ahead.
    auto stage2 = [&](int buf) {
        const float* gb = gxs + buf * 12416 + (wid - 4) * 3104;
        __builtin_amdgcn_s_setprio(1);           // consumers own the SIMD
        float xr = gb[h3], xz = gb[h3 + 1], xn = gb[h3 + 2];   // s = 0
        #pragma unroll 4
        for (int s = 0; s < TT; ++s) {
            // prefetch step s+1 (independent of the h-chain)
            float xr_n = 0.f, xz_n = 0.f, xn_n = 0.f;
            if (s < TT - 1) {
                const float* nrow = gb + (s + 1) * GXS + h3;
                xr_n = nrow[0]; xz_n = nrow[1]; xn_n = nrow[2];
            }
            f32x2 aA0 = {0.f, 0.f}, aA1 = {0.f, 0.f};
            f32x2 aN0 = {0.f, 0.f}, aN1 = {0.f, 0.f};
            const int hb = __float_as_int(hout);
            #pragma unroll
            for (int j = 0; j < 16; j += 2) {
                float s0 = __int_as_float(__builtin_amdgcn_readlane(hb, 2 * j));
                float s1 = __int_as_float(__builtin_amdgcn_readlane(hb, 2 * j + 1));
                float s2 = __int_as_float(__builtin_amdgcn_readlane(hb, 2 * j + 2));
                float s3 = __int_as_float(__builtin_amdgcn_readlane(hb, 2 * j + 3));
                f32x2 h01 = {s0, s1}, h23 = {s2, s3};
                aA0 = __builtin_elementwise_fma(wg2[j],     h01, aA0);
                aA1 = __builtin_elementwise_fma(wg2[j + 1], h23, aA1);
                aN0 = __builtin_elementwise_fma(wn2[j],     h01, aN0);
                aN1 = __builtin_elementwise_fma(wn2[j + 1], h23, aN1);
            }
            f32x2 aA = aA0 + aA1;
            f32x2 aN = aN0 + aN1;
            float accA = aA.x + aA.y;                // r-mv (half0) / z-mv (half1)
            float accN = aN.x + aN.y;                // n-mv (both halves)
            // joint sigmoid: half0 -> r, half1 -> z (one exp + one rcp)
            float xg  = (lane < 32) ? xr : xz;
            float sig = __builtin_amdgcn_rcpf(1.f + __expf(-(xg + accA)));
            float zs  = __shfl_xor(sig, 32, 64);     // half0 receives finished z
            if (lane < 32) {
                float nx = fmaf(sig, accN + bhn, xn);   // sig == r on half0
                float n  = 1.f - 2.f * __builtin_amdgcn_rcpf(__expf(2.f * nx) + 1.f);
                hout = n + zs * (hout - n);          // lanes 0-31 hold h[0..31]
            }
            xr = xr_n; xz = xz_n; xn = xn_n;
        }
        __builtin_amdgcn_s_setprio(0);
    };

    // ================= pipeline =================
    if (wid < 4) load_xtile(0);
    __syncthreads();                    // wfrag+bias ready; xs = tile 0

    if (wid < 4) stage1(0, 1);          // gxs[0] = tile 0; prefetch tile 1
    __syncthreads();                    // gxs[0] visible; xs = tile 1

    for (int k = 0; k < 32; ++k) {
        if (wid >= 4) {
            stage2(k & 1);
        } else if (k < 31) {
            stage1((k + 1) & 1, (k < 30) ? (k + 2) : -1);
        }
        __syncthreads();
    }

    if (wid >= 4 && lane < 32)
        out[(bid * 4 + (wid - 4)) * 32 + lane] = hout;
}

extern "C" void kernel_launch(void* const* d_in, const int* in_sizes, int n_in,
                              void* d_out, int out_size, void* d_ws, size_t ws_size,
                              hipStream_t stream) {
    const float* x    = (const float*)d_in[0];
    const float* W_ih = (const float*)d_in[1];
    const float* W_hh = (const float*)d_in[2];
    const float* b_ih = (const float*)d_in[3];
    const float* b_hh = (const float*)d_in[4];
    float* out = (float*)d_out;

    hipFuncSetAttribute((const void*)gru_fused11,
                        hipFuncAttributeMaxDynamicSharedMemorySize, LDS_BYTES);
    gru_fused11<<<256, 512, LDS_BYTES, stream>>>(x, W_ih, W_hh, b_ih, b_hh, out);
}